// Round 3
// baseline (748.410 us; speedup 1.0000x reference)
//
#include <hip/hip_runtime.h>
#include <stdint.h>
#include <stddef.h>

#define BATCH 16
#define NROW 2048
#define CH 128
#define NLAYER 4
#define NN_TOT (BATCH * NROW)
#define EPSV 1e-5f

typedef short short8 __attribute__((ext_vector_type(8)));
typedef float f32x4 __attribute__((ext_vector_type(4)));

static __device__ __forceinline__ unsigned short f2bf(float f) {
  union { float f; unsigned int i; } v;
  v.f = f;
  unsigned int u = v.i;
  return (unsigned short)((u + 0x7FFFu + ((u >> 16) & 1u)) >> 16);
}
// pack 8 consecutive floats -> 8 bf16
static __device__ __forceinline__ short8 pack8(const float* __restrict__ p) {
  f32x4 a = *(const f32x4*)p;
  f32x4 b = *(const f32x4*)(p + 4);
  short8 v;
  v[0] = (short)f2bf(a[0]); v[1] = (short)f2bf(a[1]);
  v[2] = (short)f2bf(a[2]); v[3] = (short)f2bf(a[3]);
  v[4] = (short)f2bf(b[0]); v[5] = (short)f2bf(b[1]);
  v[6] = (short)f2bf(b[2]); v[7] = (short)f2bf(b[3]);
  return v;
}
static __device__ __forceinline__ short8 pack8v(f32x4 a, f32x4 b) {
  short8 v;
  v[0] = (short)f2bf(a[0]); v[1] = (short)f2bf(a[1]);
  v[2] = (short)f2bf(a[2]); v[3] = (short)f2bf(a[3]);
  v[4] = (short)f2bf(b[0]); v[5] = (short)f2bf(b[1]);
  v[6] = (short)f2bf(b[2]); v[7] = (short)f2bf(b[3]);
  return v;
}

// ---- prep: finalize BN stats of previous layer, fold BN affine into next W --
// All params fp32. Wt (bf16): Wt[o][c] = s[c]*W[c][o]; cvec[o] = sum_c t[c]*W[c][o].
__global__ void prep_kernel(const float* __restrict__ Wl,
                            const float* __restrict__ gprev,
                            const float* __restrict__ bprev,
                            float* __restrict__ gsum, float* __restrict__ gsumsq,
                            unsigned short* __restrict__ Wt,
                            float* __restrict__ cvec,
                            float* __restrict__ sg, float* __restrict__ tg,
                            int first, int do_fold) {
  __shared__ float ss[CH], tt[CH];
  const int t = threadIdx.x;  // 128 threads
  float s_, t_;
  if (first) {
    s_ = 1.0f; t_ = 0.0f;
  } else {
    const float inv = 1.0f / (float)NN_TOT;
    float mu = gsum[t] * inv;
    float var = gsumsq[t] * inv - mu * mu;
    s_ = gprev[t] * rsqrtf(var + EPSV);
    t_ = bprev[t] - mu * s_;
  }
  ss[t] = s_; tt[t] = t_;
  sg[t] = s_; tg[t] = t_;
  gsum[t] = 0.0f; gsumsq[t] = 0.0f;
  __syncthreads();
  if (do_fold) {
    float acc = 0.0f;
    for (int c = 0; c < CH; ++c) {
      float w = Wl[c * CH + t];              // W[c][o=t]
      acc += tt[c] * w;
      Wt[t * CH + c] = f2bf(ss[c] * w);      // Wt[o][c] = s[c]*W[c][o]
    }
    cvec[t] = acc;
  }
}

// ---- K1: Yt[b][o][m] = (X @ W')[m][o] + cvec[o] ---------------------------
// X: fp32 [32768][128]; Wt: bf16 [o][c]. 64-row m-tiles, grid 512.
__global__ __launch_bounds__(256) void gemm1_kernel(
    const float* __restrict__ X,
    const unsigned short* __restrict__ Wt,
    const float* __restrict__ cvec,
    unsigned short* __restrict__ Yt) {       // bf16 [16][128][2048]
  __shared__ unsigned short As[64 * 128];    // 16 KB, 16 swizzled 16B slots/row
  __shared__ unsigned short Bs[128 * 128];   // 32 KB
  const int tid = threadIdx.x;
  const int m0 = blockIdx.x * 64;

#pragma unroll
  for (int j = 0; j < 4; ++j) {
    int c = tid + 256 * j;
    int r = c >> 4, slot = c & 15;
    int kc = slot ^ (r & 15);
    *(short8*)(As + c * 8) = pack8(X + (size_t)(m0 + r) * CH + kc * 8);
  }
#pragma unroll
  for (int j = 0; j < 8; ++j) {
    int c = tid + 256 * j;
    int r = c >> 4, slot = c & 15;
    int kc = slot ^ (r & 15);
    *(short8*)(Bs + c * 8) = *(const short8*)(Wt + (size_t)r * CH + kc * 8);
  }
  __syncthreads();

  const int l = tid & 63, w = tid >> 6;
  const int mq = (w >> 1) * 32, oq = (w & 1) * 64;
  const int lr = l & 15, lq = l >> 4;
  f32x4 acc[2][4] = {};

#pragma unroll
  for (int kt = 0; kt < 4; ++kt) {
    const int kc0 = kt * 4 + lq;
    const int slotK = kc0 ^ lr;               // row&15 == lr for all tile rows
    short8 a[2], b[4];
#pragma unroll
    for (int mi = 0; mi < 2; ++mi)
      a[mi] = *(const short8*)(As + (mq + mi * 16 + lr) * 128 + slotK * 8);
#pragma unroll
    for (int ni = 0; ni < 4; ++ni)
      b[ni] = *(const short8*)(Bs + (oq + ni * 16 + lr) * 128 + slotK * 8);
#pragma unroll
    for (int mi = 0; mi < 2; ++mi)
#pragma unroll
      for (int ni = 0; ni < 4; ++ni)
        acc[mi][ni] = __builtin_amdgcn_mfma_f32_16x16x32_bf16(a[mi], b[ni], acc[mi][ni], 0, 0, 0);
  }

  const int bat = m0 >> 11;
  const int mb = m0 & 2047;
  unsigned short* YtB = Yt + (size_t)bat * CH * NROW;
#pragma unroll
  for (int ni = 0; ni < 4; ++ni) {
    const int o = oq + ni * 16 + lr;          // D col = output channel
    const float cv = cvec[o];
    unsigned short* row = YtB + (size_t)o * NROW;
#pragma unroll
    for (int mi = 0; mi < 2; ++mi) {
      const int m = mb + mq + mi * 16 + lq * 4;  // D rows = m (4 per lane)
      f32x4 v = acc[mi][ni];
      short8 dummy;  // pack 4 bf16 via two halves of pack8v path
      unsigned short p0 = f2bf(v[0] + cv), p1 = f2bf(v[1] + cv);
      unsigned short p2 = f2bf(v[2] + cv), p3 = f2bf(v[3] + cv);
      unsigned long long packed = (unsigned long long)p0 | ((unsigned long long)p1 << 16) |
                                  ((unsigned long long)p2 << 32) | ((unsigned long long)p3 << 48);
      *(unsigned long long*)(row + m) = packed;
      (void)dummy;
    }
  }
}

// ---- K2: R[b][n][c] = ReLU(adj_b @ Y_b + bias)[n][c] fp32, + channel stats -
// MFMA roles: A = Yt (rows=channels), B = adj (rows=n)  => D rows=c, cols=n.
__global__ __launch_bounds__(256) void gemm2_kernel(
    const float* __restrict__ adj,            // fp32 [16][2048][2048]
    const unsigned short* __restrict__ Yt,    // bf16 [16][128][2048]
    const float* __restrict__ bias,           // fp32 [128]
    float* __restrict__ R,                    // fp32 [32768][128]  (== d_out)
    float* __restrict__ gsum, float* __restrict__ gsumsq) {
  __shared__ unsigned short As[4096];   // 128 rows x 32 el, 4 swizzled 16B slots
  __shared__ unsigned short Bs[4096];
  __shared__ float redS[2][CH];
  __shared__ float redQ[2][CH];
  const int tid = threadIdx.x;
  const int bat = blockIdx.x >> 4;
  const int n0 = (blockIdx.x & 15) * 128;
  const float* adjB = adj + (size_t)bat * NROW * NROW;
  const unsigned short* YtB = Yt + (size_t)bat * CH * NROW;

  // staging: chunk c (=tid, tid+256): row r=c>>2, slot=c&3, kc=slot^((r>>1)&3)
  const int rA = tid >> 2;
  const int kcS = (tid & 3) ^ ((rA >> 1) & 3);
  const unsigned short* gA0 = YtB + (size_t)rA * NROW + kcS * 8;
  const unsigned short* gA1 = gA0 + (size_t)64 * NROW;
  const float* gB0 = adjB + (size_t)(n0 + rA) * NROW + kcS * 8;
  const float* gB1 = gB0 + (size_t)64 * NROW;
  unsigned short* lA0 = As + tid * 8;
  unsigned short* lA1 = As + 2048 + tid * 8;
  unsigned short* lB0 = Bs + tid * 8;
  unsigned short* lB1 = Bs + 2048 + tid * 8;

  const int l = tid & 63, w = tid >> 6;
  const int cq = (w >> 1) * 64;   // channel quadrant (A rows / D rows)
  const int nq = (w & 1) * 64;    // n quadrant (B rows / D cols)
  const int lr = l & 15, lq = l >> 4;
  const int slotL = lq ^ ((lr >> 1) & 3);
  const int aoff = (cq + lr) * 32 + slotL * 8;   // element offsets
  const int boff = (nq + lr) * 32 + slotL * 8;

  f32x4 acc[4][4] = {};   // [c-tile][n-tile]

  short8 pa0 = *(const short8*)gA0;
  short8 pa1 = *(const short8*)gA1;
  f32x4 pb0a = *(const f32x4*)gB0, pb0b = *(const f32x4*)(gB0 + 4);
  f32x4 pb1a = *(const f32x4*)gB1, pb1b = *(const f32x4*)(gB1 + 4);

  for (int kt = 0; kt < 64; ++kt) {
    __syncthreads();                 // previous iteration's LDS reads done
    *(short8*)lA0 = pa0;
    *(short8*)lA1 = pa1;
    *(short8*)lB0 = pack8v(pb0a, pb0b);
    *(short8*)lB1 = pack8v(pb1a, pb1b);
    __syncthreads();
    if (kt < 63) {                   // prefetch next K-slab into registers
      const int k0 = (kt + 1) * 32;
      pa0 = *(const short8*)(gA0 + k0);
      pa1 = *(const short8*)(gA1 + k0);
      pb0a = *(const f32x4*)(gB0 + k0); pb0b = *(const f32x4*)(gB0 + k0 + 4);
      pb1a = *(const f32x4*)(gB1 + k0); pb1b = *(const f32x4*)(gB1 + k0 + 4);
    }
    short8 a[4], b[4];
#pragma unroll
    for (int mi = 0; mi < 4; ++mi) a[mi] = *(const short8*)(As + aoff + mi * 512);
#pragma unroll
    for (int ni = 0; ni < 4; ++ni) b[ni] = *(const short8*)(Bs + boff + ni * 512);
#pragma unroll
    for (int mi = 0; mi < 4; ++mi)
#pragma unroll
      for (int ni = 0; ni < 4; ++ni)
        acc[mi][ni] = __builtin_amdgcn_mfma_f32_16x16x32_bf16(a[mi], b[ni], acc[mi][ni], 0, 0, 0);
  }

  // epilogue: bias + relu + fp32 store (4 consecutive ch per lane = 16B) + stats
  float* RB = R + (size_t)bat * NROW * CH;
  f32x4 sumv[4] = {};
  f32x4 sumq[4] = {};
#pragma unroll
  for (int mi = 0; mi < 4; ++mi) {
    const int c0 = cq + mi * 16 + lq * 4;     // D rows = channels (4 per lane)
    f32x4 bia = *(const f32x4*)(bias + c0);
#pragma unroll
    for (int ni = 0; ni < 4; ++ni) {
      const int n = n0 + nq + ni * 16 + lr;   // D col = n
      f32x4 v = acc[mi][ni] + bia;
      v[0] = fmaxf(v[0], 0.0f);
      v[1] = fmaxf(v[1], 0.0f);
      v[2] = fmaxf(v[2], 0.0f);
      v[3] = fmaxf(v[3], 0.0f);
      sumv[mi] += v;
      sumq[mi] += v * v;
      *(f32x4*)(RB + (size_t)n * CH + c0) = v;
    }
  }
  // reduce over the 16 n-lanes within each quad
#pragma unroll
  for (int mi = 0; mi < 4; ++mi) {
#pragma unroll
    for (int d = 1; d < 16; d <<= 1) {
      sumv[mi][0] += __shfl_xor(sumv[mi][0], d);
      sumv[mi][1] += __shfl_xor(sumv[mi][1], d);
      sumv[mi][2] += __shfl_xor(sumv[mi][2], d);
      sumv[mi][3] += __shfl_xor(sumv[mi][3], d);
      sumq[mi][0] += __shfl_xor(sumq[mi][0], d);
      sumq[mi][1] += __shfl_xor(sumq[mi][1], d);
      sumq[mi][2] += __shfl_xor(sumq[mi][2], d);
      sumq[mi][3] += __shfl_xor(sumq[mi][3], d);
    }
  }
  const int nqi = w & 1;
  if (lr == 0) {
#pragma unroll
    for (int mi = 0; mi < 4; ++mi) {
      const int c0 = cq + mi * 16 + lq * 4;
      redS[nqi][c0 + 0] = sumv[mi][0];
      redS[nqi][c0 + 1] = sumv[mi][1];
      redS[nqi][c0 + 2] = sumv[mi][2];
      redS[nqi][c0 + 3] = sumv[mi][3];
      redQ[nqi][c0 + 0] = sumq[mi][0];
      redQ[nqi][c0 + 1] = sumq[mi][1];
      redQ[nqi][c0 + 2] = sumq[mi][2];
      redQ[nqi][c0 + 3] = sumq[mi][3];
    }
  }
  __syncthreads();
  if (tid < CH) {
    atomicAdd(gsum + tid, redS[0][tid] + redS[1][tid]);
  } else {
    const int c = tid - CH;
    atomicAdd(gsumsq + c, redQ[0][c] + redQ[1][c]);
  }
}

// ---- final BN applied in place on d_out (fp32) ------------------------------
__global__ void out_kernel(float* __restrict__ out,
                           const float* __restrict__ sg,
                           const float* __restrict__ tg) {
  const int total = NN_TOT * CH / 4;  // f32x4 chunks
  for (int idx = blockIdx.x * blockDim.x + threadIdx.x; idx < total;
       idx += gridDim.x * blockDim.x) {
    f32x4 v = *(f32x4*)(out + (size_t)idx * 4);
    const int c0 = (idx & 31) * 4;
    f32x4 s = *(const f32x4*)(sg + c0);
    f32x4 t = *(const f32x4*)(tg + c0);
    v = s * v + t;
    *(f32x4*)(out + (size_t)idx * 4) = v;
  }
}

extern "C" void kernel_launch(void* const* d_in, const int* in_sizes, int n_in,
                              void* d_out, int out_size, void* d_ws, size_t ws_size,
                              hipStream_t stream) {
  (void)in_sizes; (void)n_in; (void)out_size; (void)ws_size;
  const float* x     = (const float*)d_in[0];
  const float* adj   = (const float*)d_in[1];
  const float* W     = (const float*)d_in[2];
  const float* bvec  = (const float*)d_in[3];
  const float* gamma = (const float*)d_in[4];
  const float* beta  = (const float*)d_in[5];

  float* R = (float*)d_out;   // fp32 activations live in d_out (16.8 MB)

  char* ws = (char*)d_ws;
  unsigned short* Yt = (unsigned short*)(ws);                 // bf16, 8 MB
  unsigned short* Wt = (unsigned short*)(ws + 8388608);       // bf16, 32 KB
  float* cvec   = (float*)(ws + 8388608 + 32768);
  float* sg     = (float*)(ws + 8388608 + 33280);
  float* tg     = (float*)(ws + 8388608 + 33792);
  float* gsum   = (float*)(ws + 8388608 + 34304);
  float* gsumsq = (float*)(ws + 8388608 + 34816);

  for (int i = 0; i < NLAYER; ++i) {
    prep_kernel<<<1, 128, 0, stream>>>(
        W + (size_t)i * CH * CH,
        gamma + (size_t)(i ? (i - 1) : 0) * CH, beta + (size_t)(i ? (i - 1) : 0) * CH,
        gsum, gsumsq, Wt, cvec, sg, tg, (i == 0) ? 1 : 0, 1);
    gemm1_kernel<<<512, 256, 0, stream>>>((i == 0) ? x : R, Wt, cvec, Yt);
    gemm2_kernel<<<256, 256, 0, stream>>>(adj, Yt, bvec + (size_t)i * CH, R,
                                          gsum, gsumsq);
  }
  // finalize layer-3 stats into sg/tg (no fold)
  prep_kernel<<<1, 128, 0, stream>>>(W, gamma + 3 * CH, beta + 3 * CH,
                                     gsum, gsumsq, Wt, cvec, sg, tg, 0, 0);
  out_kernel<<<512, 256, 0, stream>>>(R, sg, tg);
}

// Round 4
// 715.310 us; speedup vs baseline: 1.0463x; 1.0463x over previous
//
#include <hip/hip_runtime.h>
#include <stdint.h>
#include <stddef.h>

#define BATCH 16
#define NROW 2048
#define CH 128
#define NLAYER 4
#define NN_TOT (BATCH * NROW)
#define EPSV 1e-5f

typedef short short8 __attribute__((ext_vector_type(8)));
typedef float f32x4 __attribute__((ext_vector_type(4)));

static __device__ __forceinline__ unsigned short f2bf(float f) {
  union { float f; unsigned int i; } v;
  v.f = f;
  unsigned int u = v.i;
  return (unsigned short)((u + 0x7FFFu + ((u >> 16) & 1u)) >> 16);
}
// pack 8 consecutive floats -> 8 bf16
static __device__ __forceinline__ short8 pack8(const float* __restrict__ p) {
  f32x4 a = *(const f32x4*)p;
  f32x4 b = *(const f32x4*)(p + 4);
  short8 v;
  v[0] = (short)f2bf(a[0]); v[1] = (short)f2bf(a[1]);
  v[2] = (short)f2bf(a[2]); v[3] = (short)f2bf(a[3]);
  v[4] = (short)f2bf(b[0]); v[5] = (short)f2bf(b[1]);
  v[6] = (short)f2bf(b[2]); v[7] = (short)f2bf(b[3]);
  return v;
}

// ---- cvt: adj fp32 -> bf16 once (268 MB -> 134 MB; makes layers 1-3 L3-hit)
__global__ __launch_bounds__(256) void cvt_kernel(
    const float* __restrict__ src, unsigned short* __restrict__ dst) {
  const int n8 = BATCH * NROW * NROW / 8;   // 8.39M chunks
  for (int i = blockIdx.x * blockDim.x + threadIdx.x; i < n8;
       i += gridDim.x * blockDim.x) {
    *(short8*)(dst + (size_t)i * 8) = pack8(src + (size_t)i * 8);
  }
}

// ---- prep: finalize BN stats of previous layer, fold BN affine into next W --
__global__ void prep_kernel(const float* __restrict__ Wl,
                            const float* __restrict__ gprev,
                            const float* __restrict__ bprev,
                            float* __restrict__ gsum, float* __restrict__ gsumsq,
                            unsigned short* __restrict__ Wt,
                            float* __restrict__ cvec,
                            float* __restrict__ sg, float* __restrict__ tg,
                            int first, int do_fold) {
  __shared__ float ss[CH], tt[CH];
  const int t = threadIdx.x;  // 128 threads
  float s_, t_;
  if (first) {
    s_ = 1.0f; t_ = 0.0f;
  } else {
    const float inv = 1.0f / (float)NN_TOT;
    float mu = gsum[t] * inv;
    float var = gsumsq[t] * inv - mu * mu;
    s_ = gprev[t] * rsqrtf(var + EPSV);
    t_ = bprev[t] - mu * s_;
  }
  ss[t] = s_; tt[t] = t_;
  sg[t] = s_; tg[t] = t_;
  gsum[t] = 0.0f; gsumsq[t] = 0.0f;
  __syncthreads();
  if (do_fold) {
    float acc = 0.0f;
    for (int c = 0; c < CH; ++c) {
      float w = Wl[c * CH + t];              // W[c][o=t]
      acc += tt[c] * w;
      Wt[t * CH + c] = f2bf(ss[c] * w);      // Wt[o][c] = s[c]*W[c][o]
    }
    cvec[t] = acc;
  }
}

// ---- K1: Yt[b][o][m] = (X @ W')[m][o] + cvec[o] ---------------------------
__global__ __launch_bounds__(256) void gemm1_kernel(
    const float* __restrict__ X,
    const unsigned short* __restrict__ Wt,
    const float* __restrict__ cvec,
    unsigned short* __restrict__ Yt) {       // bf16 [16][128][2048]
  __shared__ unsigned short As[64 * 128];    // 16 KB, 16 swizzled 16B slots/row
  __shared__ unsigned short Bs[128 * 128];   // 32 KB
  const int tid = threadIdx.x;
  const int m0 = blockIdx.x * 64;

#pragma unroll
  for (int j = 0; j < 4; ++j) {
    int c = tid + 256 * j;
    int r = c >> 4, slot = c & 15;
    int kc = slot ^ (r & 15);
    *(short8*)(As + c * 8) = pack8(X + (size_t)(m0 + r) * CH + kc * 8);
  }
#pragma unroll
  for (int j = 0; j < 8; ++j) {
    int c = tid + 256 * j;
    int r = c >> 4, slot = c & 15;
    int kc = slot ^ (r & 15);
    *(short8*)(Bs + c * 8) = *(const short8*)(Wt + (size_t)r * CH + kc * 8);
  }
  __syncthreads();

  const int l = tid & 63, w = tid >> 6;
  const int mq = (w >> 1) * 32, oq = (w & 1) * 64;
  const int lr = l & 15, lq = l >> 4;
  f32x4 acc[2][4] = {};

#pragma unroll
  for (int kt = 0; kt < 4; ++kt) {
    const int kc0 = kt * 4 + lq;
    const int slotK = kc0 ^ lr;
    short8 a[2], b[4];
#pragma unroll
    for (int mi = 0; mi < 2; ++mi)
      a[mi] = *(const short8*)(As + (mq + mi * 16 + lr) * 128 + slotK * 8);
#pragma unroll
    for (int ni = 0; ni < 4; ++ni)
      b[ni] = *(const short8*)(Bs + (oq + ni * 16 + lr) * 128 + slotK * 8);
#pragma unroll
    for (int mi = 0; mi < 2; ++mi)
#pragma unroll
      for (int ni = 0; ni < 4; ++ni)
        acc[mi][ni] = __builtin_amdgcn_mfma_f32_16x16x32_bf16(a[mi], b[ni], acc[mi][ni], 0, 0, 0);
  }

  const int bat = m0 >> 11;
  const int mb = m0 & 2047;
  unsigned short* YtB = Yt + (size_t)bat * CH * NROW;
#pragma unroll
  for (int ni = 0; ni < 4; ++ni) {
    const int o = oq + ni * 16 + lr;
    const float cv = cvec[o];
    unsigned short* row = YtB + (size_t)o * NROW;
#pragma unroll
    for (int mi = 0; mi < 2; ++mi) {
      const int m = mb + mq + mi * 16 + lq * 4;
      f32x4 v = acc[mi][ni];
      unsigned short p0 = f2bf(v[0] + cv), p1 = f2bf(v[1] + cv);
      unsigned short p2 = f2bf(v[2] + cv), p3 = f2bf(v[3] + cv);
      unsigned long long packed = (unsigned long long)p0 | ((unsigned long long)p1 << 16) |
                                  ((unsigned long long)p2 << 32) | ((unsigned long long)p3 << 48);
      *(unsigned long long*)(row + m) = packed;
    }
  }
}

// ---- K2: R[b][n][c] = ReLU(adj_b @ Y_b + bias)[n][c] fp32, + channel stats -
// Tile: 128 c x 64 n, grid 512 (2 blocks/CU). A = Yt (bf16), B = adjb (bf16).
__global__ __launch_bounds__(256) void gemm2_kernel(
    const unsigned short* __restrict__ adjb,  // bf16 [16][2048][2048]
    const unsigned short* __restrict__ Yt,    // bf16 [16][128][2048]
    const float* __restrict__ bias,           // fp32 [128]
    float* __restrict__ R,                    // fp32 [32768][128]  (== d_out)
    float* __restrict__ gsum, float* __restrict__ gsumsq) {
  __shared__ unsigned short As[128 * 32];   // 8 KB, 4 swizzled 16B slots/row
  __shared__ unsigned short Bs[64 * 32];    // 4 KB
  __shared__ float redS[2][CH];
  __shared__ float redQ[2][CH];
  const int tid = threadIdx.x;
  const int bat = blockIdx.x >> 5;
  const int n0 = (blockIdx.x & 31) * 64;
  const unsigned short* adjB = adjb + (size_t)bat * NROW * NROW;
  const unsigned short* YtB = Yt + (size_t)bat * CH * NROW;

  // staging chunk c: row r=c>>2, slot=c&3, kc = slot ^ ((r>>1)&3)
  const int rA = tid >> 2;                       // 0..63
  const int kcS = (tid & 3) ^ ((rA >> 1) & 3);
  const unsigned short* gA0 = YtB + (size_t)rA * NROW + kcS * 8;        // A rows 0..63
  const unsigned short* gA1 = gA0 + (size_t)64 * NROW;                  // A rows 64..127
  const unsigned short* gB0 = adjB + (size_t)(n0 + rA) * NROW + kcS * 8;// B rows 0..63
  unsigned short* lA0 = As + tid * 8;
  unsigned short* lA1 = As + 2048 + tid * 8;
  unsigned short* lB0 = Bs + tid * 8;

  const int l = tid & 63, w = tid >> 6;
  const int cq = (w >> 1) * 64;   // channel quadrant (A rows / D rows)
  const int nh = (w & 1) * 32;    // n half (B rows / D cols)
  const int lr = l & 15, lq = l >> 4;
  const int slotL = lq ^ ((lr >> 1) & 3);
  const int aoff = (cq + lr) * 32 + slotL * 8;
  const int boff = (nh + lr) * 32 + slotL * 8;

  f32x4 acc[4][2] = {};   // [c-tile][n-tile]

  short8 pa0 = *(const short8*)gA0;
  short8 pa1 = *(const short8*)gA1;
  short8 pb0 = *(const short8*)gB0;

  for (int kt = 0; kt < 64; ++kt) {
    __syncthreads();                 // previous iteration's LDS reads done
    *(short8*)lA0 = pa0;
    *(short8*)lA1 = pa1;
    *(short8*)lB0 = pb0;
    __syncthreads();
    if (kt < 63) {                   // prefetch next K-slab into registers
      const int k0 = (kt + 1) * 32;
      pa0 = *(const short8*)(gA0 + k0);
      pa1 = *(const short8*)(gA1 + k0);
      pb0 = *(const short8*)(gB0 + k0);
    }
    short8 a[4], b[2];
#pragma unroll
    for (int mi = 0; mi < 4; ++mi) a[mi] = *(const short8*)(As + aoff + mi * 512);
#pragma unroll
    for (int ni = 0; ni < 2; ++ni) b[ni] = *(const short8*)(Bs + boff + ni * 512);
#pragma unroll
    for (int mi = 0; mi < 4; ++mi)
#pragma unroll
      for (int ni = 0; ni < 2; ++ni)
        acc[mi][ni] = __builtin_amdgcn_mfma_f32_16x16x32_bf16(a[mi], b[ni], acc[mi][ni], 0, 0, 0);
  }

  // epilogue: bias + relu + fp32 store (4 consecutive ch per lane = 16B) + stats
  float* RB = R + (size_t)bat * NROW * CH;
  f32x4 sumv[4] = {};
  f32x4 sumq[4] = {};
#pragma unroll
  for (int mi = 0; mi < 4; ++mi) {
    const int c0 = cq + mi * 16 + lq * 4;     // D rows = channels (4 per lane)
    f32x4 bia = *(const f32x4*)(bias + c0);
#pragma unroll
    for (int ni = 0; ni < 2; ++ni) {
      const int n = n0 + nh + ni * 16 + lr;   // D col = n
      f32x4 v = acc[mi][ni] + bia;
      v[0] = fmaxf(v[0], 0.0f);
      v[1] = fmaxf(v[1], 0.0f);
      v[2] = fmaxf(v[2], 0.0f);
      v[3] = fmaxf(v[3], 0.0f);
      sumv[mi] += v;
      sumq[mi] += v * v;
      *(f32x4*)(RB + (size_t)n * CH + c0) = v;
    }
  }
  // reduce over the 16 n-lanes within each quad
#pragma unroll
  for (int mi = 0; mi < 4; ++mi) {
#pragma unroll
    for (int d = 1; d < 16; d <<= 1) {
      sumv[mi][0] += __shfl_xor(sumv[mi][0], d);
      sumv[mi][1] += __shfl_xor(sumv[mi][1], d);
      sumv[mi][2] += __shfl_xor(sumv[mi][2], d);
      sumv[mi][3] += __shfl_xor(sumv[mi][3], d);
      sumq[mi][0] += __shfl_xor(sumq[mi][0], d);
      sumq[mi][1] += __shfl_xor(sumq[mi][1], d);
      sumq[mi][2] += __shfl_xor(sumq[mi][2], d);
      sumq[mi][3] += __shfl_xor(sumq[mi][3], d);
    }
  }
  const int nqi = w & 1;
  if (lr == 0) {
#pragma unroll
    for (int mi = 0; mi < 4; ++mi) {
      const int c0 = cq + mi * 16 + lq * 4;
      redS[nqi][c0 + 0] = sumv[mi][0];
      redS[nqi][c0 + 1] = sumv[mi][1];
      redS[nqi][c0 + 2] = sumv[mi][2];
      redS[nqi][c0 + 3] = sumv[mi][3];
      redQ[nqi][c0 + 0] = sumq[mi][0];
      redQ[nqi][c0 + 1] = sumq[mi][1];
      redQ[nqi][c0 + 2] = sumq[mi][2];
      redQ[nqi][c0 + 3] = sumq[mi][3];
    }
  }
  __syncthreads();
  if (tid < CH) {
    atomicAdd(gsum + tid, redS[0][tid] + redS[1][tid]);
  } else {
    const int c = tid - CH;
    atomicAdd(gsumsq + c, redQ[0][c] + redQ[1][c]);
  }
}

// ---- final BN applied in place on d_out (fp32) ------------------------------
__global__ void out_kernel(float* __restrict__ out,
                           const float* __restrict__ sg,
                           const float* __restrict__ tg) {
  const int total = NN_TOT * CH / 4;  // f32x4 chunks
  for (int idx = blockIdx.x * blockDim.x + threadIdx.x; idx < total;
       idx += gridDim.x * blockDim.x) {
    f32x4 v = *(f32x4*)(out + (size_t)idx * 4);
    const int c0 = (idx & 31) * 4;
    f32x4 s = *(const f32x4*)(sg + c0);
    f32x4 t = *(const f32x4*)(tg + c0);
    v = s * v + t;
    *(f32x4*)(out + (size_t)idx * 4) = v;
  }
}

extern "C" void kernel_launch(void* const* d_in, const int* in_sizes, int n_in,
                              void* d_out, int out_size, void* d_ws, size_t ws_size,
                              hipStream_t stream) {
  (void)in_sizes; (void)n_in; (void)out_size; (void)ws_size;
  const float* x     = (const float*)d_in[0];
  const float* adj   = (const float*)d_in[1];
  const float* W     = (const float*)d_in[2];
  const float* bvec  = (const float*)d_in[3];
  const float* gamma = (const float*)d_in[4];
  const float* beta  = (const float*)d_in[5];

  float* R = (float*)d_out;   // fp32 activations live in d_out (16.8 MB)

  char* ws = (char*)d_ws;
  unsigned short* adjb = (unsigned short*)(ws);                   // bf16, 134 MB
  unsigned short* Yt   = (unsigned short*)(ws + 134217728);       // bf16, 8 MB
  unsigned short* Wt   = (unsigned short*)(ws + 142606336);       // bf16, 32 KB
  float* cvec   = (float*)(ws + 142606336 + 32768);
  float* sg     = (float*)(ws + 142606336 + 33280);
  float* tg     = (float*)(ws + 142606336 + 33792);
  float* gsum   = (float*)(ws + 142606336 + 34304);
  float* gsumsq = (float*)(ws + 142606336 + 34816);

  cvt_kernel<<<8192, 256, 0, stream>>>(adj, adjb);

  for (int i = 0; i < NLAYER; ++i) {
    prep_kernel<<<1, 128, 0, stream>>>(
        W + (size_t)i * CH * CH,
        gamma + (size_t)(i ? (i - 1) : 0) * CH, beta + (size_t)(i ? (i - 1) : 0) * CH,
        gsum, gsumsq, Wt, cvec, sg, tg, (i == 0) ? 1 : 0, 1);
    gemm1_kernel<<<512, 256, 0, stream>>>((i == 0) ? x : R, Wt, cvec, Yt);
    gemm2_kernel<<<512, 256, 0, stream>>>(adjb, Yt, bvec + (size_t)i * CH, R,
                                          gsum, gsumsq);
  }
  // finalize layer-3 stats into sg/tg (no fold)
  prep_kernel<<<1, 128, 0, stream>>>(W, gamma + 3 * CH, beta + 3 * CH,
                                     gsum, gsumsq, Wt, cvec, sg, tg, 0, 0);
  out_kernel<<<512, 256, 0, stream>>>(R, sg, tg);
}